// Round 4
// baseline (23.980 us; speedup 1.0000x reference)
//
#include <hip/hip_runtime.h>
#include <math.h>

#define HDIM 32
#define NSTEPS 32
#define NSECANT 8
#define RADIUSV 1.0f
#define NEARV 0.5f
#define TAUV 0.5f
#define EPSV 1e-6f

typedef float f2 __attribute__((ext_vector_type(2)));

// exchange a 32-bit value with the xor-1 partner lane (BitMode swizzle)
__device__ __forceinline__ unsigned pair_other_u(unsigned x) {
    return (unsigned)__builtin_amdgcn_ds_swizzle((int)x, 0x041F);
}

__global__ __launch_bounds__(256) void unisurf_kernel(
    const float* __restrict__ cam_loc,   // [3]
    const float* __restrict__ ray_dirs,  // [P*3]
    const float* __restrict__ W1,        // [3*HDIM]
    const float* __restrict__ b1,        // [HDIM]
    const float* __restrict__ W2,        // [HDIM]
    const float* __restrict__ b2,        // [1]
    float* __restrict__ out,             // [2*P]: d_pred then occ_surf
    int P)
{
    __shared__ float4 sW[HDIM];   // (w0, w1, w2, b1) per hidden unit
    __shared__ float  sW2[HDIM];
    __shared__ float  sB2;

    const int tid = threadIdx.x;
    if (tid < HDIM) {
        sW[tid] = make_float4(W1[tid], W1[HDIM + tid], W1[2 * HDIM + tid], b1[tid]);
        sW2[tid] = W2[tid];
    }
    if (tid == 0) sB2 = b2[0];
    __syncthreads();

    const int j = blockIdx.x * blockDim.x + tid;
    const int r = j >> 1;          // ray index: 2 threads per ray (step-split)
    if (r >= P) return;
    const int sub = j & 1;         // 0: even coarse steps, 1: odd coarse steps

    // camera (wave-uniform)
    const float cx = cam_loc[0], cy = cam_loc[1], cz = cam_loc[2];

    // ray load + normalize (duplicated in the pair)
    float dx = ray_dirs[3 * r + 0];
    float dy = ray_dirs[3 * r + 1];
    float dz = ray_dirs[3 * r + 2];
    float nrm = sqrtf(dx * dx + dy * dy + dz * dz);
    float rx = dx / nrm, ry = dy / nrm, rz = dz / nrm;

    // sphere intersection
    float rcd = rx * cx + ry * cy + rz * cz;
    float c2  = cx * cx + cy * cy + cz * cz;
    float us  = rcd * rcd - (c2 - RADIUSV * RADIUSV);
    bool  mask_int = us > 0.0f;
    float s_sq = mask_int ? sqrtf(us) : 0.0f;
    float far_raw = mask_int ? fmaxf(s_sq - rcd, 0.0f) : 0.0f;
    float farv = fmaxf(far_raw, NEARV + EPSV);

    // full per-ray factored MLP (all 32 units in this thread):
    //   a_h(d) = cW[h] + d * rW[h];  logit = sum_h relu(a_h)*w2[h] + B2
    f2 rW[HDIM / 2], cW[HDIM / 2], w2[HDIM / 2];
    #pragma unroll
    for (int h = 0; h < HDIM / 2; ++h) {
        float4 wa = sW[2 * h], wb = sW[2 * h + 1];
        rW[h] = (f2){rx * wa.x + ry * wa.y + rz * wa.z,
                     rx * wb.x + ry * wb.y + rz * wb.z};
        cW[h] = (f2){cx * wa.x + cy * wa.y + cz * wa.z + wa.w,
                     cx * wb.x + cy * wb.y + cz * wb.z + wb.w};
        w2[h] = (f2){sW2[2 * h], sW2[2 * h + 1]};
    }
    const float B2 = sB2;
    const f2 z2 = (f2){0.0f, 0.0f};

    auto logit = [&](float d) -> float {
        f2 dv = (f2){d, d};
        f2 a0 = z2, a1 = z2, a2 = z2, a3 = z2;
        #pragma unroll
        for (int h = 0; h < HDIM / 2; h += 4) {
            f2 x0 = __builtin_elementwise_fma(dv, rW[h + 0], cW[h + 0]);
            f2 x1 = __builtin_elementwise_fma(dv, rW[h + 1], cW[h + 1]);
            f2 x2 = __builtin_elementwise_fma(dv, rW[h + 2], cW[h + 2]);
            f2 x3 = __builtin_elementwise_fma(dv, rW[h + 3], cW[h + 3]);
            a0 = __builtin_elementwise_fma(__builtin_elementwise_max(x0, z2), w2[h + 0], a0);
            a1 = __builtin_elementwise_fma(__builtin_elementwise_max(x1, z2), w2[h + 1], a1);
            a2 = __builtin_elementwise_fma(__builtin_elementwise_max(x2, z2), w2[h + 2], a2);
            a3 = __builtin_elementwise_fma(__builtin_elementwise_max(x3, z2), w2[h + 3], a3);
        }
        f2 aa = (a0 + a1) + (a2 + a3);
        return (aa.x + aa.y) + B2;
    };
    auto sigm = [](float x) -> float {   // fast sigmoid: v_exp + v_rcp
        float e = __expf(-x);
        return __builtin_amdgcn_rcpf(1.0f + e);
    };

    const float STEPC = 0.03225806451612903f;  // fl(1/31)

    // coarse march: this lane evaluates 16 steps s = sub, sub+2, ..., sub+30
    // mask bit k = (logit at step sub+2k) >= 0   (== f >= 0)
    unsigned msk = 0u;
    #pragma unroll
    for (int k = 0; k < 16; ++k) {
        float t = (float)(sub + 2 * k) * STEPC;
        float dd = NEARV * (1.0f - t) + farv * t;
        float ls = logit(dd);
        msk |= (ls >= 0.0f) ? (1u << k) : 0u;
    }

    // exchange masks with partner; reconstruct even/odd views on both lanes
    unsigned om = pair_other_u(msk);
    unsigned E = sub ? om : msk;    // signs at steps 0,2,...,30
    unsigned O = sub ? msk : om;    // signs at steps 1,3,...,31

    // first free->occupied crossing: f[s]<0 && f[s+1]>=0
    unsigned candE = (~E & O) & 0xFFFFu;          // crossing at s=2k
    unsigned candO = (~O & (E >> 1)) & 0x7FFFu;   // crossing at s=2k+1
    int sE = candE ? 2 * __builtin_ctz(candE) : 1000;
    int sO = candO ? 2 * __builtin_ctz(candO) + 1 : 1000;
    int sstar = sE < sO ? sE : sO;
    bool found = sstar < 1000;
    if (!found) sstar = 0;          // reference: idx = argmax(all-false) = 0
    found = found && mask_int;

    // bracket endpoints (re-evaluate the two logits; cheaper than spilling 16)
    float tlo = (float)sstar * STEPC;
    float thi = (float)(sstar + 1) * STEPC;
    float d_lo = NEARV * (1.0f - tlo) + farv * tlo;
    float d_hi = NEARV * (1.0f - thi) + farv * thi;
    float f_lo = sigm(logit(d_lo)) - TAUV;
    float f_hi = sigm(logit(d_hi)) - TAUV;

    // secant refinement (pair-uniform, duplicated in both lanes)
    #pragma unroll 1
    for (int it = 0; it < NSECANT; ++it) {
        float den = f_hi - f_lo;
        den = (fabsf(den) < EPSV) ? EPSV : den;
        float dm = d_lo - f_lo * (d_hi - d_lo) * __builtin_amdgcn_rcpf(den);
        float fm = sigm(logit(dm)) - TAUV;
        bool neg = fm < 0.0f;
        d_lo = neg ? dm : d_lo;
        f_lo = neg ? fm : f_lo;
        d_hi = neg ? d_hi : dm;
        f_hi = neg ? f_hi : fm;
    }
    float den = f_hi - f_lo;
    den = (fabsf(den) < EPSV) ? EPSV : den;
    float d_mid = d_lo - f_lo * (d_hi - d_lo) * __builtin_amdgcn_rcpf(den);

    float d_pred = found ? d_mid : 0.0f;
    float occ_s = sigm(logit(d_pred));
    float occ_surf = found ? occ_s : 0.0f;

    if (sub == 0) out[r] = d_pred;
    else          out[P + r] = occ_surf;
}

extern "C" void kernel_launch(void* const* d_in, const int* in_sizes, int n_in,
                              void* d_out, int out_size, void* d_ws, size_t ws_size,
                              hipStream_t stream) {
    const float* cam_loc  = (const float*)d_in[0];
    const float* ray_dirs = (const float*)d_in[1];
    const float* W1       = (const float*)d_in[2];
    const float* b1       = (const float*)d_in[3];
    const float* W2       = (const float*)d_in[4];
    const float* b2       = (const float*)d_in[5];
    float* out = (float*)d_out;

    const int P = in_sizes[1] / 3;
    const int block = 256;
    const long long total = 2LL * P;           // 2 threads per ray
    const int grid = (int)((total + block - 1) / block);
    unisurf_kernel<<<grid, block, 0, stream>>>(cam_loc, ray_dirs, W1, b1, W2, b2, out, P);
}

// Round 5
// 19.838 us; speedup vs baseline: 1.2088x; 1.2088x over previous
//
#include <hip/hip_runtime.h>
#include <math.h>

#define HDIM 32
#define NSTEPS 32
#define NSECANT 8
#define RADIUSV 1.0f
#define NEARV 0.5f
#define TAUV 0.5f
#define EPSV 1e-6f

typedef float f2 __attribute__((ext_vector_type(2)));

__global__ __launch_bounds__(256, 2) void unisurf_kernel(
    const float* __restrict__ cam_loc,   // [3]
    const float* __restrict__ ray_dirs,  // [P*3]
    const float* __restrict__ W1,        // [3*HDIM]
    const float* __restrict__ b1,        // [HDIM]
    const float* __restrict__ W2,        // [HDIM]
    const float* __restrict__ b2,        // [1]
    float* __restrict__ out,             // [2*P]: d_pred then occ_surf
    int P)
{
    __shared__ float4 sW[HDIM];   // (w0, w1, w2, b1) per hidden unit
    __shared__ float  sW2[HDIM];
    __shared__ float  sB2;

    const int tid = threadIdx.x;
    if (tid < HDIM) {
        sW[tid] = make_float4(W1[tid], W1[HDIM + tid], W1[2 * HDIM + tid], b1[tid]);
        sW2[tid] = W2[tid];
    }
    if (tid == 0) sB2 = b2[0];
    __syncthreads();

    const int r = blockIdx.x * blockDim.x + tid;
    if (r >= P) return;

    // camera (wave-uniform)
    const float cx = cam_loc[0], cy = cam_loc[1], cz = cam_loc[2];

    // ray load + normalize
    float dx = ray_dirs[3 * r + 0];
    float dy = ray_dirs[3 * r + 1];
    float dz = ray_dirs[3 * r + 2];
    float nrm = sqrtf(dx * dx + dy * dy + dz * dz);
    float rx = dx / nrm, ry = dy / nrm, rz = dz / nrm;

    // sphere intersection
    float rcd = rx * cx + ry * cy + rz * cz;
    float c2  = cx * cx + cy * cy + cz * cz;
    float us  = rcd * rcd - (c2 - RADIUSV * RADIUSV);
    bool  mask_int = us > 0.0f;
    float s_sq = mask_int ? sqrtf(us) : 0.0f;
    float far_raw = mask_int ? fmaxf(s_sq - rcd, 0.0f) : 0.0f;
    float farv = fmaxf(far_raw, NEARV + EPSV);

    // per-ray factored MLP:  a_h(d) = cW[h] + d*rW[h];
    // logit = sum_h relu(a_h)*w2[h] + B2
    f2 rW[HDIM / 2], cW[HDIM / 2], w2[HDIM / 2];
    #pragma unroll
    for (int h = 0; h < HDIM / 2; ++h) {
        float4 wa = sW[2 * h], wb = sW[2 * h + 1];
        rW[h] = (f2){rx * wa.x + ry * wa.y + rz * wa.z,
                     rx * wb.x + ry * wb.y + rz * wb.z};
        cW[h] = (f2){cx * wa.x + cy * wa.y + cz * wa.z + wa.w,
                     cx * wb.x + cy * wb.y + cz * wb.z + wb.w};
        w2[h] = (f2){sW2[2 * h], sW2[2 * h + 1]};
    }
    const float B2 = sB2;
    const f2 z2 = (f2){0.0f, 0.0f};

    // two independent logit evals, instruction-interleaved for ILP
    auto logit2 = [&](float dA, float dB, float& lA, float& lB) {
        f2 dvA = (f2){dA, dA}, dvB = (f2){dB, dB};
        f2 aA0 = z2, aA1 = z2, aB0 = z2, aB1 = z2;
        #pragma unroll
        for (int h = 0; h < HDIM / 2; h += 2) {
            f2 xA0 = __builtin_elementwise_fma(dvA, rW[h + 0], cW[h + 0]);
            f2 xB0 = __builtin_elementwise_fma(dvB, rW[h + 0], cW[h + 0]);
            f2 xA1 = __builtin_elementwise_fma(dvA, rW[h + 1], cW[h + 1]);
            f2 xB1 = __builtin_elementwise_fma(dvB, rW[h + 1], cW[h + 1]);
            aA0 = __builtin_elementwise_fma(__builtin_elementwise_max(xA0, z2), w2[h + 0], aA0);
            aB0 = __builtin_elementwise_fma(__builtin_elementwise_max(xB0, z2), w2[h + 0], aB0);
            aA1 = __builtin_elementwise_fma(__builtin_elementwise_max(xA1, z2), w2[h + 1], aA1);
            aB1 = __builtin_elementwise_fma(__builtin_elementwise_max(xB1, z2), w2[h + 1], aB1);
        }
        f2 sA = aA0 + aA1, sB = aB0 + aB1;
        lA = (sA.x + sA.y) + B2;
        lB = (sB.x + sB.y) + B2;
    };
    // single logit eval, 4 accumulator chains
    auto logit = [&](float d) -> float {
        f2 dv = (f2){d, d};
        f2 a0 = z2, a1 = z2, a2 = z2, a3 = z2;
        #pragma unroll
        for (int h = 0; h < HDIM / 2; h += 4) {
            f2 x0 = __builtin_elementwise_fma(dv, rW[h + 0], cW[h + 0]);
            f2 x1 = __builtin_elementwise_fma(dv, rW[h + 1], cW[h + 1]);
            f2 x2 = __builtin_elementwise_fma(dv, rW[h + 2], cW[h + 2]);
            f2 x3 = __builtin_elementwise_fma(dv, rW[h + 3], cW[h + 3]);
            a0 = __builtin_elementwise_fma(__builtin_elementwise_max(x0, z2), w2[h + 0], a0);
            a1 = __builtin_elementwise_fma(__builtin_elementwise_max(x1, z2), w2[h + 1], a1);
            a2 = __builtin_elementwise_fma(__builtin_elementwise_max(x2, z2), w2[h + 2], a2);
            a3 = __builtin_elementwise_fma(__builtin_elementwise_max(x3, z2), w2[h + 3], a3);
        }
        f2 aa = (a0 + a1) + (a2 + a3);
        return (aa.x + aa.y) + B2;
    };
    auto sigm = [](float x) -> float {   // fast sigmoid: v_exp + v_rcp
        float e = __expf(-x);
        return __builtin_amdgcn_rcpf(1.0f + e);
    };

    const float STEPC = 0.03225806451612903f;  // fl(1/31)

    // coarse march: evals (k, k+16) interleaved; bit s of msk = (logit_s >= 0)
    unsigned msk = 0u;
    #pragma unroll 1
    for (int k = 0; k < 16; ++k) {
        float tA = (float)k * STEPC;
        float tB = (float)(k + 16) * STEPC;
        float dA = NEARV * (1.0f - tA) + farv * tA;
        float dB = NEARV * (1.0f - tB) + farv * tB;
        float lA, lB;
        logit2(dA, dB, lA, lB);
        unsigned bA = (lA >= 0.0f) ? (1u << k) : 0u;
        unsigned bB = (lB >= 0.0f) ? (1u << (k + 16)) : 0u;
        msk |= bA | bB;
    }

    // first free->occupied crossing: f[s]<0 && f[s+1]>=0
    unsigned cand = (~msk & (msk >> 1)) & 0x7FFFFFFFu;
    bool found = cand != 0u;
    int sstar = found ? __builtin_ctz(cand) : 0;   // ref: argmax(all-false)=0
    found = found && mask_int;

    // bracket endpoints (interleaved re-eval)
    float tlo = (float)sstar * STEPC;
    float thi = (float)(sstar + 1) * STEPC;
    float d_lo = NEARV * (1.0f - tlo) + farv * tlo;
    float d_hi = NEARV * (1.0f - thi) + farv * thi;
    float lLo, lHi;
    logit2(d_lo, d_hi, lLo, lHi);
    float f_lo = sigm(lLo) - TAUV;
    float f_hi = sigm(lHi) - TAUV;

    // secant refinement
    #pragma unroll 1
    for (int it = 0; it < NSECANT; ++it) {
        float den = f_hi - f_lo;
        den = (fabsf(den) < EPSV) ? EPSV : den;
        float dm = d_lo - f_lo * (d_hi - d_lo) * __builtin_amdgcn_rcpf(den);
        float fm = sigm(logit(dm)) - TAUV;
        bool neg = fm < 0.0f;
        d_lo = neg ? dm : d_lo;
        f_lo = neg ? fm : f_lo;
        d_hi = neg ? d_hi : dm;
        f_hi = neg ? f_hi : fm;
    }
    float den = f_hi - f_lo;
    den = (fabsf(den) < EPSV) ? EPSV : den;
    float d_mid = d_lo - f_lo * (d_hi - d_lo) * __builtin_amdgcn_rcpf(den);

    float d_pred = found ? d_mid : 0.0f;
    float occ_s = sigm(logit(d_pred));
    float occ_surf = found ? occ_s : 0.0f;

    out[r]     = d_pred;
    out[P + r] = occ_surf;
}

extern "C" void kernel_launch(void* const* d_in, const int* in_sizes, int n_in,
                              void* d_out, int out_size, void* d_ws, size_t ws_size,
                              hipStream_t stream) {
    const float* cam_loc  = (const float*)d_in[0];
    const float* ray_dirs = (const float*)d_in[1];
    const float* W1       = (const float*)d_in[2];
    const float* b1       = (const float*)d_in[3];
    const float* W2       = (const float*)d_in[4];
    const float* b2       = (const float*)d_in[5];
    float* out = (float*)d_out;

    const int P = in_sizes[1] / 3;
    const int block = 256;
    const int grid = (P + block - 1) / block;
    unisurf_kernel<<<grid, block, 0, stream>>>(cam_loc, ray_dirs, W1, b1, W2, b2, out, P);
}

// Round 6
// 19.300 us; speedup vs baseline: 1.2425x; 1.0279x over previous
//
#include <hip/hip_runtime.h>
#include <math.h>

#define HDIM 32
#define NSTEPS 32
#define NSECANT 8
#define RADIUSV 1.0f
#define NEARV 0.5f
#define TAUV 0.5f
#define EPSV 1e-6f

typedef float f2 __attribute__((ext_vector_type(2)));

__global__ __launch_bounds__(256, 2) void unisurf_kernel(
    const float* __restrict__ cam_loc,   // [3]
    const float* __restrict__ ray_dirs,  // [P*3]
    const float* __restrict__ W1,        // [3*HDIM]
    const float* __restrict__ b1,        // [HDIM]
    const float* __restrict__ W2,        // [HDIM]
    const float* __restrict__ b2,        // [1]
    float* __restrict__ out,             // [2*P]: d_pred then occ_surf
    int P)
{
    __shared__ float4 sW[HDIM];   // (w0, w1, w2, b1) per hidden unit
    __shared__ float  sCW[HDIM];  // cam·W1 + b1  (ray-independent)
    __shared__ float  sW2[HDIM];
    __shared__ float  sB2;

    const int tid = threadIdx.x;
    if (tid < HDIM) {
        float c0 = cam_loc[0], c1 = cam_loc[1], c2l = cam_loc[2];
        float4 w4 = make_float4(W1[tid], W1[HDIM + tid], W1[2 * HDIM + tid], b1[tid]);
        sW[tid] = w4;
        sCW[tid] = c0 * w4.x + c1 * w4.y + c2l * w4.z + w4.w;
        sW2[tid] = W2[tid];
        if (tid == 0) sB2 = b2[0];
    }
    __syncthreads();

    const int r = blockIdx.x * blockDim.x + tid;
    if (r >= P) return;

    // camera (wave-uniform)
    const float cx = cam_loc[0], cy = cam_loc[1], cz = cam_loc[2];

    // ray load + fast normalize (rsq ~1e-7 rel; threshold 3.5e-2)
    float dx = ray_dirs[3 * r + 0];
    float dy = ray_dirs[3 * r + 1];
    float dz = ray_dirs[3 * r + 2];
    float inv = __builtin_amdgcn_rsqf(dx * dx + dy * dy + dz * dz);
    float rx = dx * inv, ry = dy * inv, rz = dz * inv;

    // sphere intersection
    float rcd = rx * cx + ry * cy + rz * cz;
    float c2  = cx * cx + cy * cy + cz * cz;
    float us  = rcd * rcd - (c2 - RADIUSV * RADIUSV);
    bool  mask_int = us > 0.0f;
    float s_sq = mask_int ? sqrtf(us) : 0.0f;
    float far_raw = mask_int ? fmaxf(s_sq - rcd, 0.0f) : 0.0f;
    float farv = fmaxf(far_raw, NEARV + EPSV);

    // per-ray factored MLP: a_h(d) = cW[h] + d*rW[h]; logit = Σ relu(a)*w2 + B2
    // cW comes precomputed from LDS; rW = r·W1 computed here.
    f2 rW[HDIM / 2], cW[HDIM / 2], w2[HDIM / 2];
    #pragma unroll
    for (int h = 0; h < HDIM / 2; ++h) {
        float4 wa = sW[2 * h], wb = sW[2 * h + 1];
        rW[h] = (f2){rx * wa.x + ry * wa.y + rz * wa.z,
                     rx * wb.x + ry * wb.y + rz * wb.z};
        cW[h] = (f2){sCW[2 * h], sCW[2 * h + 1]};
        w2[h] = (f2){sW2[2 * h], sW2[2 * h + 1]};
    }
    const float B2 = sB2;
    const f2 z2 = (f2){0.0f, 0.0f};

    // four independent logit evals, instruction-interleaved (2 acc chains each)
    auto logit4 = [&](float d0, float d1, float d2v, float d3,
                      float& l0, float& l1, float& l2, float& l3) {
        f2 dv0 = (f2){d0, d0}, dv1 = (f2){d1, d1};
        f2 dv2 = (f2){d2v, d2v}, dv3 = (f2){d3, d3};
        f2 a0a = z2, a0b = z2, a1a = z2, a1b = z2;
        f2 a2a = z2, a2b = z2, a3a = z2, a3b = z2;
        #pragma unroll
        for (int h = 0; h < HDIM / 2; h += 2) {
            f2 x0a = __builtin_elementwise_fma(dv0, rW[h + 0], cW[h + 0]);
            f2 x1a = __builtin_elementwise_fma(dv1, rW[h + 0], cW[h + 0]);
            f2 x2a = __builtin_elementwise_fma(dv2, rW[h + 0], cW[h + 0]);
            f2 x3a = __builtin_elementwise_fma(dv3, rW[h + 0], cW[h + 0]);
            f2 x0b = __builtin_elementwise_fma(dv0, rW[h + 1], cW[h + 1]);
            f2 x1b = __builtin_elementwise_fma(dv1, rW[h + 1], cW[h + 1]);
            f2 x2b = __builtin_elementwise_fma(dv2, rW[h + 1], cW[h + 1]);
            f2 x3b = __builtin_elementwise_fma(dv3, rW[h + 1], cW[h + 1]);
            a0a = __builtin_elementwise_fma(__builtin_elementwise_max(x0a, z2), w2[h + 0], a0a);
            a1a = __builtin_elementwise_fma(__builtin_elementwise_max(x1a, z2), w2[h + 0], a1a);
            a2a = __builtin_elementwise_fma(__builtin_elementwise_max(x2a, z2), w2[h + 0], a2a);
            a3a = __builtin_elementwise_fma(__builtin_elementwise_max(x3a, z2), w2[h + 0], a3a);
            a0b = __builtin_elementwise_fma(__builtin_elementwise_max(x0b, z2), w2[h + 1], a0b);
            a1b = __builtin_elementwise_fma(__builtin_elementwise_max(x1b, z2), w2[h + 1], a1b);
            a2b = __builtin_elementwise_fma(__builtin_elementwise_max(x2b, z2), w2[h + 1], a2b);
            a3b = __builtin_elementwise_fma(__builtin_elementwise_max(x3b, z2), w2[h + 1], a3b);
        }
        f2 s0 = a0a + a0b, s1 = a1a + a1b, s2 = a2a + a2b, s3 = a3a + a3b;
        l0 = (s0.x + s0.y) + B2;
        l1 = (s1.x + s1.y) + B2;
        l2 = (s2.x + s2.y) + B2;
        l3 = (s3.x + s3.y) + B2;
    };
    // two interleaved evals (bracket)
    auto logit2 = [&](float dA, float dB, float& lA, float& lB) {
        f2 dvA = (f2){dA, dA}, dvB = (f2){dB, dB};
        f2 aA0 = z2, aA1 = z2, aB0 = z2, aB1 = z2;
        #pragma unroll
        for (int h = 0; h < HDIM / 2; h += 2) {
            f2 xA0 = __builtin_elementwise_fma(dvA, rW[h + 0], cW[h + 0]);
            f2 xB0 = __builtin_elementwise_fma(dvB, rW[h + 0], cW[h + 0]);
            f2 xA1 = __builtin_elementwise_fma(dvA, rW[h + 1], cW[h + 1]);
            f2 xB1 = __builtin_elementwise_fma(dvB, rW[h + 1], cW[h + 1]);
            aA0 = __builtin_elementwise_fma(__builtin_elementwise_max(xA0, z2), w2[h + 0], aA0);
            aB0 = __builtin_elementwise_fma(__builtin_elementwise_max(xB0, z2), w2[h + 0], aB0);
            aA1 = __builtin_elementwise_fma(__builtin_elementwise_max(xA1, z2), w2[h + 1], aA1);
            aB1 = __builtin_elementwise_fma(__builtin_elementwise_max(xB1, z2), w2[h + 1], aB1);
        }
        f2 sA = aA0 + aA1, sB = aB0 + aB1;
        lA = (sA.x + sA.y) + B2;
        lB = (sB.x + sB.y) + B2;
    };
    // single logit eval, 4 accumulator chains
    auto logit = [&](float d) -> float {
        f2 dv = (f2){d, d};
        f2 a0 = z2, a1 = z2, a2 = z2, a3 = z2;
        #pragma unroll
        for (int h = 0; h < HDIM / 2; h += 4) {
            f2 x0 = __builtin_elementwise_fma(dv, rW[h + 0], cW[h + 0]);
            f2 x1 = __builtin_elementwise_fma(dv, rW[h + 1], cW[h + 1]);
            f2 x2 = __builtin_elementwise_fma(dv, rW[h + 2], cW[h + 2]);
            f2 x3 = __builtin_elementwise_fma(dv, rW[h + 3], cW[h + 3]);
            a0 = __builtin_elementwise_fma(__builtin_elementwise_max(x0, z2), w2[h + 0], a0);
            a1 = __builtin_elementwise_fma(__builtin_elementwise_max(x1, z2), w2[h + 1], a1);
            a2 = __builtin_elementwise_fma(__builtin_elementwise_max(x2, z2), w2[h + 2], a2);
            a3 = __builtin_elementwise_fma(__builtin_elementwise_max(x3, z2), w2[h + 3], a3);
        }
        f2 aa = (a0 + a1) + (a2 + a3);
        return (aa.x + aa.y) + B2;
    };
    auto sigm = [](float x) -> float {   // fast sigmoid: v_exp + v_rcp
        float e = __expf(-x);
        return __builtin_amdgcn_rcpf(1.0f + e);
    };

    const float STEPC = 0.03225806451612903f;  // fl(1/31)

    // coarse march: 8 iters × 4 interleaved evals; bit s of msk = (logit_s >= 0)
    unsigned msk = 0u;
    #pragma unroll 1
    for (int k = 0; k < 8; ++k) {
        float t0 = (float)k * STEPC;
        float t1 = (float)(k + 8) * STEPC;
        float t2 = (float)(k + 16) * STEPC;
        float t3 = (float)(k + 24) * STEPC;
        float dd0 = NEARV * (1.0f - t0) + farv * t0;
        float dd1 = NEARV * (1.0f - t1) + farv * t1;
        float dd2 = NEARV * (1.0f - t2) + farv * t2;
        float dd3 = NEARV * (1.0f - t3) + farv * t3;
        float l0, l1, l2, l3;
        logit4(dd0, dd1, dd2, dd3, l0, l1, l2, l3);
        msk |= (l0 >= 0.0f) ? (1u << k) : 0u;
        msk |= (l1 >= 0.0f) ? (1u << (k + 8)) : 0u;
        msk |= (l2 >= 0.0f) ? (1u << (k + 16)) : 0u;
        msk |= (l3 >= 0.0f) ? (1u << (k + 24)) : 0u;
    }

    // first free->occupied crossing: f[s]<0 && f[s+1]>=0
    unsigned cand = (~msk & (msk >> 1)) & 0x7FFFFFFFu;
    bool found = cand != 0u;
    int sstar = found ? __builtin_ctz(cand) : 0;   // ref: argmax(all-false)=0
    found = found && mask_int;

    // bracket endpoints
    float tlo = (float)sstar * STEPC;
    float thi = (float)(sstar + 1) * STEPC;
    float d_lo = NEARV * (1.0f - tlo) + farv * tlo;
    float d_hi = NEARV * (1.0f - thi) + farv * thi;
    float f_lo, f_hi;                 // logit-space secant state
    logit2(d_lo, d_hi, f_lo, f_hi);

    // secant refinement in logit space (same root: sigmoid(l)=tau <=> l=0)
    #pragma unroll 1
    for (int it = 0; it < NSECANT; ++it) {
        float den = f_hi - f_lo;
        den = (fabsf(den) < EPSV) ? EPSV : den;
        float dm = d_lo - f_lo * (d_hi - d_lo) * __builtin_amdgcn_rcpf(den);
        float fm = logit(dm);
        bool neg = fm < 0.0f;
        d_lo = neg ? dm : d_lo;
        f_lo = neg ? fm : f_lo;
        d_hi = neg ? d_hi : dm;
        f_hi = neg ? f_hi : fm;
    }
    float den = f_hi - f_lo;
    den = (fabsf(den) < EPSV) ? EPSV : den;
    float d_mid = d_lo - f_lo * (d_hi - d_lo) * __builtin_amdgcn_rcpf(den);

    float d_pred = found ? d_mid : 0.0f;
    float occ_s = sigm(logit(d_pred));
    float occ_surf = found ? occ_s : 0.0f;

    out[r]     = d_pred;
    out[P + r] = occ_surf;
}

extern "C" void kernel_launch(void* const* d_in, const int* in_sizes, int n_in,
                              void* d_out, int out_size, void* d_ws, size_t ws_size,
                              hipStream_t stream) {
    const float* cam_loc  = (const float*)d_in[0];
    const float* ray_dirs = (const float*)d_in[1];
    const float* W1       = (const float*)d_in[2];
    const float* b1       = (const float*)d_in[3];
    const float* W2       = (const float*)d_in[4];
    const float* b2       = (const float*)d_in[5];
    float* out = (float*)d_out;

    const int P = in_sizes[1] / 3;
    const int block = 256;
    const int grid = (P + block - 1) / block;
    unisurf_kernel<<<grid, block, 0, stream>>>(cam_loc, ray_dirs, W1, b1, W2, b2, out, P);
}